// Round 10
// baseline (1209.098 us; speedup 1.0000x reference)
//
#include <hip/hip_runtime.h>
#include <hip/hip_bf16.h>
#include <math.h>

#define B_   2
#define S_   1024
#define D_   1024
#define H_   16
#define HD_  64
#define NL_  6
#define DFF_ 4096

typedef __bf16 bf16_t;
typedef bf16_t bf16x8 __attribute__((ext_vector_type(8)));
typedef bf16_t bf16x4 __attribute__((ext_vector_type(4)));
typedef float  f32x4  __attribute__((ext_vector_type(4)));

__device__ __forceinline__ float gelu_exact(float x) {
    return 0.5f * x * (1.0f + erff(x * 0.70710678118654752f));
}

// async global->LDS, 16B per lane; LDS dest is wave-uniform base + lane*16
__device__ __forceinline__ void gload16(const bf16_t* g, bf16_t* l) {
    __builtin_amdgcn_global_load_lds(
        (const __attribute__((address_space(1))) void*)g,
        (__attribute__((address_space(3))) void*)l, 16, 0, 0);
}

// ---------------- y = x + pos (pos broadcast over batch); fp32 + bf16 out ----------------
__global__ __launch_bounds__(256) void add_pos_kernel(
    const float* __restrict__ x, const float* __restrict__ pos,
    float* __restrict__ y, bf16_t* __restrict__ yb)
{
    int idx = blockIdx.x * 256 + threadIdx.x;      // float4 index, [0, 524288)
    f32x4 xv = *(const f32x4*)&x[idx * 4];
    f32x4 pv = *(const f32x4*)&pos[(idx & 262143) * 4];  // S*D/4 = 262144
    f32x4 o = xv + pv;
    *(f32x4*)&y[idx * 4] = o;
    *(bf16x4*)&yb[idx * 4] = __builtin_convertvector(o, bf16x4);
}

// ---------------- QKV projection via MFMA (staged) ----------------
__global__ __launch_bounds__(256) void qkv_mfma_kernel(
    const bf16_t* __restrict__ yb,
    const float* __restrict__ Wq, const float* __restrict__ bq,
    const float* __restrict__ Wk, const float* __restrict__ bk,
    const float* __restrict__ Wv, const float* __restrict__ bv,
    bf16_t* __restrict__ q, bf16_t* __restrict__ k, bf16_t* __restrict__ v)
{
    __shared__ __align__(16) bf16_t As[128][72];
    __shared__ __align__(16) bf16_t Wt[3][64][72];   // W^T: [n][k], bf16

    int tid = threadIdx.x;
    long m0 = (long)blockIdx.x * 128;

#pragma unroll
    for (int it = 0; it < 4; ++it) {
        int c = it * 256 + tid;            // [0,1024) x8 elems
        int row = c >> 3, col = (c & 7) * 8;
        *(bf16x8*)&As[row][col] = *(const bf16x8*)&yb[(m0 + row) * 64 + col];
    }
#pragma unroll
    for (int it = 0; it < 16; ++it) {
        int i = it * 256 + tid;            // [0,4096)
        int r = i >> 6, c = i & 63;
        Wt[0][c][r] = (bf16_t)Wq[i];
        Wt[1][c][r] = (bf16_t)Wk[i];
        Wt[2][c][r] = (bf16_t)Wv[i];
    }
    __syncthreads();

    int wave = tid >> 6, lane = tid & 63;
    int quad = lane >> 4, l16 = lane & 15;
    int wm = wave * 32;

    bf16x8 a[2][2];
#pragma unroll
    for (int i = 0; i < 2; ++i)
#pragma unroll
        for (int ks = 0; ks < 2; ++ks)
            a[i][ks] = *(bf16x8*)&As[wm + i * 16 + l16][ks * 32 + quad * 8];

    f32x4 acc[3][2][4];
#pragma unroll
    for (int o = 0; o < 3; ++o)
#pragma unroll
        for (int i = 0; i < 2; ++i)
#pragma unroll
            for (int j = 0; j < 4; ++j) acc[o][i][j] = (f32x4)0.f;

#pragma unroll
    for (int o = 0; o < 3; ++o)
#pragma unroll
        for (int j = 0; j < 4; ++j) {
            bf16x8 b0 = *(bf16x8*)&Wt[o][j * 16 + l16][quad * 8];
            bf16x8 b1 = *(bf16x8*)&Wt[o][j * 16 + l16][32 + quad * 8];
#pragma unroll
            for (int i = 0; i < 2; ++i) {
                acc[o][i][j] = __builtin_amdgcn_mfma_f32_16x16x32_bf16(a[i][0], b0, acc[o][i][j], 0, 0, 0);
                acc[o][i][j] = __builtin_amdgcn_mfma_f32_16x16x32_bf16(a[i][1], b1, acc[o][i][j], 0, 0, 0);
            }
        }

    bf16_t* outs[3] = { q, k, v };
    const float* biases[3] = { bq, bk, bv };
#pragma unroll
    for (int o = 0; o < 3; ++o)
#pragma unroll
        for (int j = 0; j < 4; ++j) {
            int col = j * 16 + l16;
            float bias = biases[o][col];
#pragma unroll
            for (int i = 0; i < 2; ++i) {
                long rbase = m0 + wm + i * 16 + quad * 4;
#pragma unroll
                for (int r = 0; r < 4; ++r)
                    outs[o][(rbase + r) * 64 + col] = (bf16_t)(acc[o][i][j][r] + bias);
            }
        }
}

// ---------------- V transpose: vb [b,s,h,d] -> vT [b,h,d,s] ----------------
__global__ __launch_bounds__(256) void vtrans_kernel(
    const bf16_t* __restrict__ vb, bf16_t* __restrict__ vT)
{
    __shared__ __align__(16) bf16_t L[32][72];
    int tid = threadIdx.x;
    int s0 = blockIdx.x * 32;
    int bh = blockIdx.y;
    int b = bh >> 4, h = bh & 15;
    int sr = tid >> 3, dc = (tid & 7) * 8;
    *(bf16x8*)&L[sr][dc] =
        *(const bf16x8*)&vb[(((long)b * S_ + s0 + sr) * H_ + h) * HD_ + dc];
    __syncthreads();
    int dr = tid >> 2, sg = (tid & 3) * 8;
    bf16x8 o;
#pragma unroll
    for (int j = 0; j < 8; ++j) o[j] = L[sg + j][dr];
    *(bf16x8*)&vT[((long)bh * HD_ + dr) * S_ + s0 + sg] = o;
}

// ---------------- causal flash attention, swapped-QK bf16 MFMA, 64q x 64kv ----------------
// Load-balance permutation: q-tile index = perm[bx] with perm = [0..7, 15..8],
// so perm[x]+perm[x+8]=15 -> balanced heavy+light pairs across XCDs.
__global__ __launch_bounds__(256) void attn_mfma_kernel(
    const bf16_t* __restrict__ Q, const bf16_t* __restrict__ K,
    const bf16_t* __restrict__ VT, bf16_t* __restrict__ Ob)
{
    __shared__ __align__(16) bf16_t Ks[64][72];       // [kv][d]
    __shared__ __align__(16) bf16_t Vt[64][72];       // [d][kv]
    __shared__ __align__(16) bf16_t Ps[4][16][72];    // per-wave P tile [q][kv]

    int tid = threadIdx.x;
    int wave = tid >> 6, lane = tid & 63;
    int quad = lane >> 4, l16 = lane & 15;
    int qidx = (blockIdx.x < 8) ? (int)blockIdx.x : 23 - (int)blockIdx.x;
    int q0 = qidx * 64;
    int bh = blockIdx.y;
    int b = bh >> 4, h = bh & 15;
    int qw = q0 + wave * 16;
    const float scale = 0.125f;             // 1/sqrt(64)
    const float MASKED = -1.25e19f;         // -1e20 * scale, per reference order

    const bf16_t* Qbase = Q + (((long)b * S_ + qw + l16) * H_ + h) * HD_;
    bf16x8 aq0 = *(const bf16x8*)&Qbase[quad * 8];        // B-frag: col=q(l16), k=d
    bf16x8 aq1 = *(const bf16x8*)&Qbase[32 + quad * 8];

    float mrun = -3.0e38f, lrun = 0.f;      // state for q = qw + l16 (replicated over quads)
    f32x4 oacc[4];
#pragma unroll
    for (int n = 0; n < 4; ++n) oacc[n] = (f32x4)0.f;

    int srow = tid >> 3, scol = (tid & 7) * 8;   // staging: 2 halves of 32 rows x 64 cols
    const bf16_t* VTbase = VT + ((long)bh * HD_ ) * S_;
    int qg = qw + l16;

    int nkt = qidx + 1;                     // 64-kv tiles for this block
    for (int kt = 0; kt < nkt; ++kt) {
        int k0 = kt * 64;
        __syncthreads();
#pragma unroll
        for (int half = 0; half < 2; ++half) {
            int row = half * 32 + srow;
            *(bf16x8*)&Ks[row][scol] =
                *(const bf16x8*)&K[(((long)b * S_ + k0 + row) * H_ + h) * HD_ + scol];
            *(bf16x8*)&Vt[row][scol] =
                *(const bf16x8*)&VTbase[(long)row * S_ + k0 + scol];
        }
        __syncthreads();

        if (k0 > qw + 15) continue;          // fully-masked tile for this wave

        f32x4 sc[4];
#pragma unroll
        for (int n = 0; n < 4; ++n) sc[n] = (f32x4)0.f;
#pragma unroll
        for (int n = 0; n < 4; ++n) {
            bf16x8 ak0 = *(bf16x8*)&Ks[n * 16 + l16][quad * 8];       // A-frag: row=kv(l16), k=d
            bf16x8 ak1 = *(bf16x8*)&Ks[n * 16 + l16][32 + quad * 8];
            sc[n] = __builtin_amdgcn_mfma_f32_16x16x32_bf16(ak0, aq0, sc[n], 0, 0, 0);
            sc[n] = __builtin_amdgcn_mfma_f32_16x16x32_bf16(ak1, aq1, sc[n], 0, 0, 0);
        }
        // sc[n][r]: score for kv = k0 + n*16 + quad*4 + r, q = qw + l16
        float pmax = MASKED;
#pragma unroll
        for (int n = 0; n < 4; ++n)
#pragma unroll
            for (int r = 0; r < 4; ++r) {
                int kv = k0 + n * 16 + quad * 4 + r;
                float sv = (kv <= qg) ? sc[n][r] * scale : MASKED;
                sc[n][r] = sv;
                pmax = fmaxf(pmax, sv);
            }
        pmax = fmaxf(pmax, __shfl_xor(pmax, 16));
        pmax = fmaxf(pmax, __shfl_xor(pmax, 32));
        float mnew = fmaxf(mrun, pmax);
        float ls = 0.f;
#pragma unroll
        for (int n = 0; n < 4; ++n)
#pragma unroll
            for (int r = 0; r < 4; ++r) {
                float pv = __expf(sc[n][r] - mnew);
                sc[n][r] = pv;
                ls += pv;
            }
        ls += __shfl_xor(ls, 16);
        ls += __shfl_xor(ls, 32);
        float alpha = __expf(mrun - mnew);
        lrun = lrun * alpha + ls;
        mrun = mnew;

        // pack P[q=l16][kv 0..63] to LDS (4 x bf16x4, conflict-light b64 writes)
#pragma unroll
        for (int n = 0; n < 4; ++n)
            *(bf16x4*)&Ps[wave][l16][n * 16 + quad * 4] =
                __builtin_convertvector(sc[n], bf16x4);

        f32x4 av;
#pragma unroll
        for (int r = 0; r < 4; ++r) av[r] = __shfl(alpha, quad * 4 + r);

        bf16x8 pa0 = *(bf16x8*)&Ps[wave][l16][quad * 8];        // A-frag: row=q, k=kv 0..31
        bf16x8 pa1 = *(bf16x8*)&Ps[wave][l16][32 + quad * 8];   // kv 32..63
#pragma unroll
        for (int n = 0; n < 4; ++n) {
            bf16x8 bv0 = *(bf16x8*)&Vt[n * 16 + l16][quad * 8];       // B-frag: col=d, k=kv 0..31
            bf16x8 bv1 = *(bf16x8*)&Vt[n * 16 + l16][32 + quad * 8];  // kv 32..63
            f32x4 c = oacc[n] * av;
            c = __builtin_amdgcn_mfma_f32_16x16x32_bf16(pa0, bv0, c, 0, 0, 0);
            oacc[n] = __builtin_amdgcn_mfma_f32_16x16x32_bf16(pa1, bv1, c, 0, 0, 0);
        }
    }

    float inv = 1.0f / lrun;
    f32x4 iv;
#pragma unroll
    for (int r = 0; r < 4; ++r) iv[r] = __shfl(inv, quad * 4 + r);
#pragma unroll
    for (int r = 0; r < 4; ++r) {
        long rowbase = (((long)b * S_ + qw + quad * 4 + r) * H_ + h) * HD_;
#pragma unroll
        for (int n = 0; n < 4; ++n)
            Ob[rowbase + n * 16 + l16] = (bf16_t)(oacc[n][r] * iv[r]);
    }
}

// ---------------- ALL-layer weight transpose + fp32->bf16 (one launch, vectorized writes) ----------------
// Source tile 64(Kd) x 32(Nd); output tile 32 x 64 written as bf16x8 (16B/lane,
// 8 lanes per contiguous 128B output row). Per layer: Wfc 512, W1 2048, W2 2048
// tiles -> 4608/layer, 27648 blocks total. Dst per layer (bf16 elems):
// WfcT +0 (1Mi), W1T +1Mi (4Mi), W2T +5Mi (4Mi).
__global__ __launch_bounds__(256) void tconv_all_kernel(
    const float* __restrict__ Wfc, const float* __restrict__ W1,
    const float* __restrict__ W2, bf16_t* __restrict__ WTall)
{
    int id = blockIdx.x;
    int layer = id / 4608;
    int r = id - layer * 4608;
    const float* W; bf16_t* Wt; int Kd, Nd, tix;
    if (r < 512)       { W = Wfc + (size_t)layer * 1048576; Wt = WTall + (size_t)layer * 9437184;           Kd = 1024; Nd = 1024; tix = r; }
    else if (r < 2560) { W = W1  + (size_t)layer * 4194304; Wt = WTall + (size_t)layer * 9437184 + 1048576; Kd = 1024; Nd = 4096; tix = r - 512; }
    else               { W = W2  + (size_t)layer * 4194304; Wt = WTall + (size_t)layer * 9437184 + 5242880; Kd = 4096; Nd = 1024; tix = r - 2560; }
    int ntx = Nd >> 5;                      // Nd/32 tiles along N
    int by = tix / ntx, bx = tix - by * ntx;  // by: Kd/64 tile, bx: Nd/32 tile

    __shared__ float t[64][33];
    int tid = threadIdx.x;
    int tx = tid & 31, ty = tid >> 5;       // (32, 8)
#pragma unroll
    for (int i = 0; i < 8; ++i)
        t[ty + i * 8][tx] = W[(size_t)(by * 64 + ty + i * 8) * Nd + bx * 32 + tx];
    __syncthreads();
    int c = tid >> 3, rg = (tid & 7) * 8;   // out-row (src col) c, col-group rg
    bf16x8 o;
#pragma unroll
    for (int j = 0; j < 8; ++j) o[j] = (bf16_t)t[rg + j][c];
    *(bf16x8*)&Wt[(size_t)(bx * 32 + c) * Kd + by * 64 + rg] = o;
}

// ---------------- bf16 MFMA GEMM: C[MxN] = A[MxK] * Bt[NxK]^T + bias ----------------
// BM=128, BN=64, BK=32. 3-stage software pipeline with COUNTED vmcnt.
__global__ __launch_bounds__(256) void gemm_bt_kernel(
    const bf16_t* __restrict__ A, const bf16_t* __restrict__ Bt,
    const float* __restrict__ bias, float* __restrict__ Cf,
    bf16_t* __restrict__ Cb, int M, int N, int K, int act, size_t pstride)
{
    __shared__ __align__(16) bf16_t As[3][128 * 32];   // 3 x 8 KB
    __shared__ __align__(16) bf16_t Bs[3][64 * 32];    // 3 x 4 KB
    int tid = threadIdx.x;
    int wave = tid >> 6, lane = tid & 63;
    int quad = lane >> 4, l16 = lane & 15;
    int m0 = blockIdx.x * 128;
    int n0 = blockIdx.y * 64;
    int Kc = K / gridDim.z;
    int kbeg = blockIdx.z * Kc;
    float* Cfp = Cf ? Cf + (size_t)blockIdx.z * pstride : nullptr;

    int wm = (wave >> 1) * 64, wn = (wave & 1) * 32;

    int srow = lane >> 2;
    int sslot = (lane & 3) ^ (srow & 3);          // pre-swizzled global source slot
    int rslot = (quad ^ (l16 & 3)) * 8;

    f32x4 acc[4][2];
#pragma unroll
    for (int i = 0; i < 4; ++i)
#pragma unroll
        for (int j = 0; j < 2; ++j) acc[i][j] = (f32x4)0.f;

    const bf16_t* Ab = A + (size_t)(m0 + srow) * K + sslot * 8;
    const bf16_t* Bb = Bt + (size_t)(n0 + wave * 16 + srow) * K + sslot * 8;
    int seg0 = wave * 2;
    int nt = Kc >> 5;

    #define STAGE(t, buf) do {                                                      \
        int kk_ = kbeg + (t) * 32;                                                  \
        gload16(Ab + (size_t)seg0 * 16 * K + kk_, &As[(buf)][seg0 * 512]);          \
        gload16(Ab + (size_t)(seg0 + 1) * 16 * K + kk_, &As[(buf)][(seg0+1) * 512]);\
        gload16(Bb + kk_, &Bs[(buf)][wave * 512]);                                  \
    } while (0)

    #define COMPUTE(buf) do {                                                       \
        bf16x8 af[4], bfr[2];                                                       \
        _Pragma("unroll")                                                           \
        for (int i = 0; i < 4; ++i)                                                 \
            af[i] = *(bf16x8*)&As[(buf)][(wm + i * 16 + l16) * 32 + rslot];         \
        _Pragma("unroll")                                                           \
        for (int j = 0; j < 2; ++j)                                                 \
            bfr[j] = *(bf16x8*)&Bs[(buf)][(wn + j * 16 + l16) * 32 + rslot];        \
        _Pragma("unroll")                                                           \
        for (int i = 0; i < 4; ++i)                                                 \
            _Pragma("unroll")                                                       \
            for (int j = 0; j < 2; ++j)                                             \
                acc[i][j] = __builtin_amdgcn_mfma_f32_16x16x32_bf16(                \
                    af[i], bfr[j], acc[i][j], 0, 0, 0);                             \
    } while (0)

    STAGE(0, 0);
    STAGE(1, 1);

    int cur = 0, pf = 2;
    for (int t = 0; t < nt - 1; ++t) {
        asm volatile("s_waitcnt vmcnt(3)" ::: "memory");
        __builtin_amdgcn_s_barrier();
        __builtin_amdgcn_sched_barrier(0);
        if (t + 2 < nt) STAGE(t + 2, pf);
        COMPUTE(cur);
        cur = (cur == 2) ? 0 : cur + 1;
        pf  = (pf  == 2) ? 0 : pf  + 1;
    }
    asm volatile("s_waitcnt vmcnt(0)" ::: "memory");
    __builtin_amdgcn_s_barrier();
    __builtin_amdgcn_sched_barrier(0);
    COMPUTE(cur);

    #undef STAGE
    #undef COMPUTE

#pragma unroll
    for (int j = 0; j < 2; ++j) {
        int col = n0 + wn + j * 16 + l16;
        float bv = (bias && blockIdx.z == 0) ? bias[col] : 0.f;
#pragma unroll
        for (int i = 0; i < 4; ++i) {
            int rbase = m0 + wm + i * 16 + quad * 4;
#pragma unroll
            for (int r = 0; r < 4; ++r) {
                float vv = acc[i][j][r] + bv;
                if (act == 1) vv = gelu_exact(vv);
                if (Cfp) Cfp[(size_t)(rbase + r) * N + col] = vv;
                if (Cb) Cb[(size_t)(rbase + r) * N + col] = (bf16_t)vv;
            }
        }
    }
}

// ---------------- fused (partial-sum) residual add + LayerNorm (row = one block) ----------------
__global__ __launch_bounds__(256) void ln_fused_kernel(
    const float* __restrict__ a0, const float* __restrict__ a1,
    const float* __restrict__ b,
    const float* __restrict__ w, const float* __restrict__ beta,
    float* __restrict__ out, bf16_t* __restrict__ outb)
{
    long row = blockIdx.x;
    int tid = threadIdx.x;
    f32x4 z = *(const f32x4*)&a0[row * D_ + tid * 4];
    if (a1) z += *(const f32x4*)&a1[row * D_ + tid * 4];
    if (b)  z += *(const f32x4*)&b[row * D_ + tid * 4];
    float s  = z[0] + z[1] + z[2] + z[3];
    float ss = z[0]*z[0] + z[1]*z[1] + z[2]*z[2] + z[3]*z[3];
#pragma unroll
    for (int off = 32; off >= 1; off >>= 1) {
        s  += __shfl_down(s, off);
        ss += __shfl_down(ss, off);
    }
    __shared__ float red[8];
    int lane = tid & 63, wid = tid >> 6;
    if (lane == 0) { red[wid * 2] = s; red[wid * 2 + 1] = ss; }
    __syncthreads();
    s  = red[0] + red[2] + red[4] + red[6];
    ss = red[1] + red[3] + red[5] + red[7];
    float mean = s * (1.0f / D_);
    float var  = ss * (1.0f / D_) - mean * mean;
    float rs = rsqrtf(var + 1e-5f);
    f32x4 wv = *(const f32x4*)&w[tid * 4];
    f32x4 bv = *(const f32x4*)&beta[tid * 4];
    f32x4 o = (z - mean) * rs * wv + bv;
    *(f32x4*)&out[row * D_ + tid * 4] = o;
    if (outb) *(bf16x4*)&outb[row * D_ + tid * 4] = __builtin_convertvector(o, bf16x4);
}

// ---------------- host launch ----------------
extern "C" void kernel_launch(void* const* d_in, const int* in_sizes, int n_in,
                              void* d_out, int out_size, void* d_ws, size_t ws_size,
                              hipStream_t stream)
{
    (void)in_sizes; (void)n_in; (void)out_size; (void)ws_size;
    const float* x    = (const float*)d_in[0];
    const float* pos  = (const float*)d_in[1];
    const float* Wq   = (const float*)d_in[2];
    const float* bq   = (const float*)d_in[3];
    const float* Wk   = (const float*)d_in[4];
    const float* bk   = (const float*)d_in[5];
    const float* Wv   = (const float*)d_in[6];
    const float* bv   = (const float*)d_in[7];
    const float* Wfc  = (const float*)d_in[8];
    const float* bfc  = (const float*)d_in[9];
    const float* ln1w = (const float*)d_in[10];
    const float* ln1b = (const float*)d_in[11];
    const float* ln2w = (const float*)d_in[12];
    const float* ln2b = (const float*)d_in[13];
    const float* W1   = (const float*)d_in[14];
    const float* b1   = (const float*)d_in[15];
    const float* W2   = (const float*)d_in[16];
    const float* b2   = (const float*)d_in[17];
    const float* lnfw = (const float*)d_in[18];
    const float* lnfb = (const float*)d_in[19];

    const size_t MB = 1 << 20;
    char* ws = (char*)d_ws;
    float*  y    = (float*)(ws);             //  0-8   fp32 activations
    bf16_t* yb   = (bf16_t*)(ws + 8 * MB);   //  8-12  bf16 activations
    bf16_t* qb   = (bf16_t*)(ws + 12 * MB);  // 12-16
    bf16_t* kb   = (bf16_t*)(ws + 16 * MB);  // 16-20
    bf16_t* vb   = (bf16_t*)(ws + 20 * MB);  // 20-24
    bf16_t* ob   = (bf16_t*)(ws + 24 * MB);  // 24-28
    float*  t1a  = (float*)(ws + 12 * MB);   // 12-20  Wfc partial 0 (qb/kb dead after attn)
    float*  t1b  = (float*)(ws + 28 * MB);   // 28-36  Wfc partial 1 (aliases 'add'; ln1 reduces in place)
    float*  t2a  = (float*)(ws + 12 * MB);   // 12-20  FFN2 partial 0
    float*  t2b  = (float*)(ws + 20 * MB);   // 20-28  FFN2 partial 1 (vb/ob dead by then)
    float*  add  = (float*)(ws + 28 * MB);   // 28-36
    bf16_t* addb = (bf16_t*)(ws + 36 * MB);  // 36-40
    bf16_t* vTb  = (bf16_t*)(ws + 40 * MB);  // 40-44  V^T [b,h,d,s] (ffb region, dead here)
    bf16_t* ffb  = (bf16_t*)(ws + 40 * MB);  // 40-56
    bf16_t* WTall= (bf16_t*)(ws + 64 * MB);  // 64-172 all-layer weight transposes (18 MB/layer)

    const size_t pstride_wfc  = (size_t)16 * MB / sizeof(float); // t1b - t1a
    const size_t pstride_ffn2 = (size_t)8 * MB / sizeof(float);  // t2b - t2a
    const size_t LSTRIDE = 9437184;                              // bf16 elems per layer

    // all weight transposes in ONE launch, off the per-layer critical path
    tconv_all_kernel<<<27648, 256, 0, stream>>>(Wfc, W1, W2, WTall);

    add_pos_kernel<<<2048, 256, 0, stream>>>(x, pos, y, yb);

    for (int i = 0; i < NL_; ++i) {
        bf16_t* WfcT = WTall + (size_t)i * LSTRIDE;
        bf16_t* W1T  = WfcT + 1048576;
        bf16_t* W2T  = WfcT + 5242880;

        qkv_mfma_kernel<<<256, 256, 0, stream>>>(
            yb, Wq + i * 4096, bq + i * 64, Wk + i * 4096, bk + i * 64,
            Wv + i * 4096, bv + i * 64, qb, kb, vb);

        vtrans_kernel<<<dim3(32, 32), 256, 0, stream>>>(vb, vTb);

        attn_mfma_kernel<<<dim3(16, 32), 256, 0, stream>>>(qb, kb, vTb, ob);

        // ---- attention output projection: split-K=2, BN=64 -> 512 blocks ----
        gemm_bt_kernel<<<dim3(16, 16, 2), 256, 0, stream>>>(
            ob, WfcT, bfc + i * D_, t1a, nullptr, 2048, D_, D_, 0, pstride_wfc);

        ln_fused_kernel<<<2048, 256, 0, stream>>>(
            t1a, t1b, y, ln1w + i * D_, ln1b + i * D_, add, addb);

        // ---- FFN1: BN=64 -> 1024 blocks (4 blocks/CU) ----
        gemm_bt_kernel<<<dim3(16, 64, 1), 256, 0, stream>>>(
            addb, W1T, b1 + i * DFF_, nullptr, ffb, 2048, DFF_, D_, 1, 0);

        // ---- FFN2: split-K=2, BN=64 -> 512 blocks ----
        gemm_bt_kernel<<<dim3(16, 16, 2), 256, 0, stream>>>(
            ffb, W2T, b2 + i * D_, t2a, nullptr, 2048, D_, DFF_, 0, pstride_ffn2);

        ln_fused_kernel<<<2048, 256, 0, stream>>>(
            t2a, t2b, add, ln2w + i * D_, ln2b + i * D_, y, yb);
    }

    ln_fused_kernel<<<2048, 256, 0, stream>>>(
        y, nullptr, nullptr, lnfw, lnfb, (float*)d_out, nullptr);
}

// Round 12
// 1188.483 us; speedup vs baseline: 1.0173x; 1.0173x over previous
//
#include <hip/hip_runtime.h>
#include <hip/hip_bf16.h>
#include <math.h>

#define B_   2
#define S_   1024
#define D_   1024
#define H_   16
#define HD_  64
#define NL_  6
#define DFF_ 4096

typedef __bf16 bf16_t;
typedef bf16_t bf16x8 __attribute__((ext_vector_type(8)));
typedef bf16_t bf16x4 __attribute__((ext_vector_type(4)));
typedef float  f32x4  __attribute__((ext_vector_type(4)));

__device__ __forceinline__ float gelu_exact(float x) {
    return 0.5f * x * (1.0f + erff(x * 0.70710678118654752f));
}

// async global->LDS, 16B per lane; LDS dest is wave-uniform base + lane*16
__device__ __forceinline__ void gload16(const bf16_t* g, bf16_t* l) {
    __builtin_amdgcn_global_load_lds(
        (const __attribute__((address_space(1))) void*)g,
        (__attribute__((address_space(3))) void*)l, 16, 0, 0);
}

// ---------------- y = x + pos (pos broadcast over batch); fp32 + bf16 out ----------------
__global__ __launch_bounds__(256) void add_pos_kernel(
    const float* __restrict__ x, const float* __restrict__ pos,
    float* __restrict__ y, bf16_t* __restrict__ yb)
{
    int idx = blockIdx.x * 256 + threadIdx.x;      // float4 index, [0, 524288)
    f32x4 xv = *(const f32x4*)&x[idx * 4];
    f32x4 pv = *(const f32x4*)&pos[(idx & 262143) * 4];  // S*D/4 = 262144
    f32x4 o = xv + pv;
    *(f32x4*)&y[idx * 4] = o;
    *(bf16x4*)&yb[idx * 4] = __builtin_convertvector(o, bf16x4);
}

// ---------------- QKV projection via MFMA (staged) ----------------
__global__ __launch_bounds__(256) void qkv_mfma_kernel(
    const bf16_t* __restrict__ yb,
    const float* __restrict__ Wq, const float* __restrict__ bq,
    const float* __restrict__ Wk, const float* __restrict__ bk,
    const float* __restrict__ Wv, const float* __restrict__ bv,
    bf16_t* __restrict__ q, bf16_t* __restrict__ k, bf16_t* __restrict__ v)
{
    __shared__ __align__(16) bf16_t As[128][72];
    __shared__ __align__(16) bf16_t Wt[3][64][72];   // W^T: [n][k], bf16

    int tid = threadIdx.x;
    long m0 = (long)blockIdx.x * 128;

#pragma unroll
    for (int it = 0; it < 4; ++it) {
        int c = it * 256 + tid;            // [0,1024) x8 elems
        int row = c >> 3, col = (c & 7) * 8;
        *(bf16x8*)&As[row][col] = *(const bf16x8*)&yb[(m0 + row) * 64 + col];
    }
#pragma unroll
    for (int it = 0; it < 16; ++it) {
        int i = it * 256 + tid;            // [0,4096)
        int r = i >> 6, c = i & 63;
        Wt[0][c][r] = (bf16_t)Wq[i];
        Wt[1][c][r] = (bf16_t)Wk[i];
        Wt[2][c][r] = (bf16_t)Wv[i];
    }
    __syncthreads();

    int wave = tid >> 6, lane = tid & 63;
    int quad = lane >> 4, l16 = lane & 15;
    int wm = wave * 32;

    bf16x8 a[2][2];
#pragma unroll
    for (int i = 0; i < 2; ++i)
#pragma unroll
        for (int ks = 0; ks < 2; ++ks)
            a[i][ks] = *(bf16x8*)&As[wm + i * 16 + l16][ks * 32 + quad * 8];

    f32x4 acc[3][2][4];
#pragma unroll
    for (int o = 0; o < 3; ++o)
#pragma unroll
        for (int i = 0; i < 2; ++i)
#pragma unroll
            for (int j = 0; j < 4; ++j) acc[o][i][j] = (f32x4)0.f;

#pragma unroll
    for (int o = 0; o < 3; ++o)
#pragma unroll
        for (int j = 0; j < 4; ++j) {
            bf16x8 b0 = *(bf16x8*)&Wt[o][j * 16 + l16][quad * 8];
            bf16x8 b1 = *(bf16x8*)&Wt[o][j * 16 + l16][32 + quad * 8];
#pragma unroll
            for (int i = 0; i < 2; ++i) {
                acc[o][i][j] = __builtin_amdgcn_mfma_f32_16x16x32_bf16(a[i][0], b0, acc[o][i][j], 0, 0, 0);
                acc[o][i][j] = __builtin_amdgcn_mfma_f32_16x16x32_bf16(a[i][1], b1, acc[o][i][j], 0, 0, 0);
            }
        }

    bf16_t* outs[3] = { q, k, v };
    const float* biases[3] = { bq, bk, bv };
#pragma unroll
    for (int o = 0; o < 3; ++o)
#pragma unroll
        for (int j = 0; j < 4; ++j) {
            int col = j * 16 + l16;
            float bias = biases[o][col];
#pragma unroll
            for (int i = 0; i < 2; ++i) {
                long rbase = m0 + wm + i * 16 + quad * 4;
#pragma unroll
                for (int r = 0; r < 4; ++r)
                    outs[o][(rbase + r) * 64 + col] = (bf16_t)(acc[o][i][j][r] + bias);
            }
        }
}

// ---------------- V transpose: vb [b,s,h,d] -> vT [b,h,d,s] ----------------
__global__ __launch_bounds__(256) void vtrans_kernel(
    const bf16_t* __restrict__ vb, bf16_t* __restrict__ vT)
{
    __shared__ __align__(16) bf16_t L[32][72];
    int tid = threadIdx.x;
    int s0 = blockIdx.x * 32;
    int bh = blockIdx.y;
    int b = bh >> 4, h = bh & 15;
    int sr = tid >> 3, dc = (tid & 7) * 8;
    *(bf16x8*)&L[sr][dc] =
        *(const bf16x8*)&vb[(((long)b * S_ + s0 + sr) * H_ + h) * HD_ + dc];
    __syncthreads();
    int dr = tid >> 2, sg = (tid & 3) * 8;
    bf16x8 o;
#pragma unroll
    for (int j = 0; j < 8; ++j) o[j] = L[sg + j][dr];
    *(bf16x8*)&vT[((long)bh * HD_ + dr) * S_ + s0 + sg] = o;
}

// ---------------- causal flash attention, swapped-QK bf16 MFMA, 64q x 64kv ----------------
__global__ __launch_bounds__(256) void attn_mfma_kernel(
    const bf16_t* __restrict__ Q, const bf16_t* __restrict__ K,
    const bf16_t* __restrict__ VT, bf16_t* __restrict__ Ob)
{
    __shared__ __align__(16) bf16_t Ks[64][72];       // [kv][d]
    __shared__ __align__(16) bf16_t Vt[64][72];       // [d][kv]
    __shared__ __align__(16) bf16_t Ps[4][16][72];    // per-wave P tile [q][kv]

    int tid = threadIdx.x;
    int wave = tid >> 6, lane = tid & 63;
    int quad = lane >> 4, l16 = lane & 15;
    int q0 = blockIdx.x * 64;
    int bh = blockIdx.y;
    int b = bh >> 4, h = bh & 15;
    int qw = q0 + wave * 16;
    const float scale = 0.125f;             // 1/sqrt(64)
    const float MASKED = -1.25e19f;         // -1e20 * scale, per reference order

    const bf16_t* Qbase = Q + (((long)b * S_ + qw + l16) * H_ + h) * HD_;
    bf16x8 aq0 = *(const bf16x8*)&Qbase[quad * 8];        // B-frag: col=q(l16), k=d
    bf16x8 aq1 = *(const bf16x8*)&Qbase[32 + quad * 8];

    float mrun = -3.0e38f, lrun = 0.f;      // state for q = qw + l16 (replicated over quads)
    f32x4 oacc[4];
#pragma unroll
    for (int n = 0; n < 4; ++n) oacc[n] = (f32x4)0.f;

    int srow = tid >> 3, scol = (tid & 7) * 8;   // staging: 2 halves of 32 rows x 64 cols
    const bf16_t* VTbase = VT + ((long)bh * HD_ ) * S_;
    int qg = qw + l16;

    int nkt = blockIdx.x + 1;               // 64-kv tiles for this block
    for (int kt = 0; kt < nkt; ++kt) {
        int k0 = kt * 64;
        __syncthreads();
#pragma unroll
        for (int half = 0; half < 2; ++half) {
            int row = half * 32 + srow;
            *(bf16x8*)&Ks[row][scol] =
                *(const bf16x8*)&K[(((long)b * S_ + k0 + row) * H_ + h) * HD_ + scol];
            *(bf16x8*)&Vt[row][scol] =
                *(const bf16x8*)&VTbase[(long)row * S_ + k0 + scol];
        }
        __syncthreads();

        if (k0 > qw + 15) continue;          // fully-masked tile for this wave

        f32x4 sc[4];
#pragma unroll
        for (int n = 0; n < 4; ++n) sc[n] = (f32x4)0.f;
#pragma unroll
        for (int n = 0; n < 4; ++n) {
            bf16x8 ak0 = *(bf16x8*)&Ks[n * 16 + l16][quad * 8];       // A-frag: row=kv(l16), k=d
            bf16x8 ak1 = *(bf16x8*)&Ks[n * 16 + l16][32 + quad * 8];
            sc[n] = __builtin_amdgcn_mfma_f32_16x16x32_bf16(ak0, aq0, sc[n], 0, 0, 0);
            sc[n] = __builtin_amdgcn_mfma_f32_16x16x32_bf16(ak1, aq1, sc[n], 0, 0, 0);
        }
        // sc[n][r]: score for kv = k0 + n*16 + quad*4 + r, q = qw + l16
        float pmax = MASKED;
#pragma unroll
        for (int n = 0; n < 4; ++n)
#pragma unroll
            for (int r = 0; r < 4; ++r) {
                int kv = k0 + n * 16 + quad * 4 + r;
                float sv = (kv <= qg) ? sc[n][r] * scale : MASKED;
                sc[n][r] = sv;
                pmax = fmaxf(pmax, sv);
            }
        pmax = fmaxf(pmax, __shfl_xor(pmax, 16));
        pmax = fmaxf(pmax, __shfl_xor(pmax, 32));
        float mnew = fmaxf(mrun, pmax);
        float ls = 0.f;
#pragma unroll
        for (int n = 0; n < 4; ++n)
#pragma unroll
            for (int r = 0; r < 4; ++r) {
                float pv = __expf(sc[n][r] - mnew);
                sc[n][r] = pv;
                ls += pv;
            }
        ls += __shfl_xor(ls, 16);
        ls += __shfl_xor(ls, 32);
        float alpha = __expf(mrun - mnew);
        lrun = lrun * alpha + ls;
        mrun = mnew;

        // pack P[q=l16][kv 0..63] to LDS (4 x bf16x4, conflict-light b64 writes)
#pragma unroll
        for (int n = 0; n < 4; ++n)
            *(bf16x4*)&Ps[wave][l16][n * 16 + quad * 4] =
                __builtin_convertvector(sc[n], bf16x4);

        f32x4 av;
#pragma unroll
        for (int r = 0; r < 4; ++r) av[r] = __shfl(alpha, quad * 4 + r);

        bf16x8 pa0 = *(bf16x8*)&Ps[wave][l16][quad * 8];        // A-frag: row=q, k=kv 0..31
        bf16x8 pa1 = *(bf16x8*)&Ps[wave][l16][32 + quad * 8];   // kv 32..63
#pragma unroll
        for (int n = 0; n < 4; ++n) {
            bf16x8 bv0 = *(bf16x8*)&Vt[n * 16 + l16][quad * 8];       // B-frag: col=d, k=kv 0..31
            bf16x8 bv1 = *(bf16x8*)&Vt[n * 16 + l16][32 + quad * 8];  // kv 32..63
            f32x4 c = oacc[n] * av;
            c = __builtin_amdgcn_mfma_f32_16x16x32_bf16(pa0, bv0, c, 0, 0, 0);
            oacc[n] = __builtin_amdgcn_mfma_f32_16x16x32_bf16(pa1, bv1, c, 0, 0, 0);
        }
    }

    float inv = 1.0f / lrun;
    f32x4 iv;
#pragma unroll
    for (int r = 0; r < 4; ++r) iv[r] = __shfl(inv, quad * 4 + r);
#pragma unroll
    for (int r = 0; r < 4; ++r) {
        long rowbase = (((long)b * S_ + qw + quad * 4 + r) * H_ + h) * HD_;
#pragma unroll
        for (int n = 0; n < 4; ++n)
            Ob[rowbase + n * 16 + l16] = (bf16_t)(oacc[n][r] * iv[r]);
    }
}

// ---------------- ALL-layer weight transpose + fp32->bf16 (one launch, vectorized writes) ----------------
__global__ __launch_bounds__(256) void tconv_all_kernel(
    const float* __restrict__ Wfc, const float* __restrict__ W1,
    const float* __restrict__ W2, bf16_t* __restrict__ WTall)
{
    int id = blockIdx.x;
    int layer = id / 4608;
    int r = id - layer * 4608;
    const float* W; bf16_t* Wt; int Kd, Nd, tix;
    if (r < 512)       { W = Wfc + (size_t)layer * 1048576; Wt = WTall + (size_t)layer * 9437184;           Kd = 1024; Nd = 1024; tix = r; }
    else if (r < 2560) { W = W1  + (size_t)layer * 4194304; Wt = WTall + (size_t)layer * 9437184 + 1048576; Kd = 1024; Nd = 4096; tix = r - 512; }
    else               { W = W2  + (size_t)layer * 4194304; Wt = WTall + (size_t)layer * 9437184 + 5242880; Kd = 4096; Nd = 1024; tix = r - 2560; }
    int ntx = Nd >> 5;
    int by = tix / ntx, bx = tix - by * ntx;

    __shared__ float t[64][33];
    int tid = threadIdx.x;
    int tx = tid & 31, ty = tid >> 5;       // (32, 8)
#pragma unroll
    for (int i = 0; i < 8; ++i)
        t[ty + i * 8][tx] = W[(size_t)(by * 64 + ty + i * 8) * Nd + bx * 32 + tx];
    __syncthreads();
    int c = tid >> 3, rg = (tid & 7) * 8;
    bf16x8 o;
#pragma unroll
    for (int j = 0; j < 8; ++j) o[j] = (bf16_t)t[rg + j][c];
    *(bf16x8*)&Wt[(size_t)(bx * 32 + c) * Kd + by * 64 + rg] = o;
}

// ---------------- bf16 MFMA GEMM: C[MxN] = A[MxK] * Bt[NxK]^T + bias ----------------
// BM=128, BN templated (64 or 128), BK=32. 3-stage pipeline, COUNTED vmcnt
// (L=3 for BN=64, L=4 for BN=128; never 0 in main loop). LDS linear [row][32]
// with 4-slot XOR swizzle. grid.z = K-split; partial z -> Cf + z*pstride.
template<int BN>
__global__ __launch_bounds__(256) void gemm_bt_kernel(
    const bf16_t* __restrict__ A, const bf16_t* __restrict__ Bt,
    const float* __restrict__ bias, float* __restrict__ Cf,
    bf16_t* __restrict__ Cb, int M, int N, int K, int act, size_t pstride)
{
    __shared__ __align__(16) bf16_t As[3][128 * 32];   // 3 x 8 KB
    __shared__ __align__(16) bf16_t Bs[3][BN * 32];    // 3 x 4/8 KB
    int tid = threadIdx.x;
    int wave = tid >> 6, lane = tid & 63;
    int quad = lane >> 4, l16 = lane & 15;
    int m0 = blockIdx.x * 128;
    int n0 = blockIdx.y * BN;
    int Kc = K / gridDim.z;
    int kbeg = blockIdx.z * Kc;
    float* Cfp = Cf ? Cf + (size_t)blockIdx.z * pstride : nullptr;

    constexpr int WN = BN / 2;       // wave tile N
    constexpr int NJ = WN / 16;      // 4 for BN=128, 2 for BN=64
    int wm = (wave >> 1) * 64, wn = (wave & 1) * WN;

    int srow = lane >> 2;
    int sslot = (lane & 3) ^ (srow & 3);          // pre-swizzled global source slot
    int rslot = (quad ^ (l16 & 3)) * 8;

    f32x4 acc[4][NJ];
#pragma unroll
    for (int i = 0; i < 4; ++i)
#pragma unroll
        for (int j = 0; j < NJ; ++j) acc[i][j] = (f32x4)0.f;

    const bf16_t* Ab = A + (size_t)(m0 + srow) * K + sslot * 8;
    const bf16_t* Bb = Bt + (size_t)(n0 + srow + (BN == 64 ? wave * 16 : 0)) * K + sslot * 8;
    int seg0 = wave * 2;
    int nt = Kc >> 5;

    // stage tile t into buffer buf: A = 2 segs/wave; B = 1 seg (BN=64) or 2 segs (BN=128)
    #define STAGE(t, buf) do {                                                      \
        int kk_ = kbeg + (t) * 32;                                                  \
        gload16(Ab + (size_t)seg0 * 16 * K + kk_, &As[(buf)][seg0 * 512]);          \
        gload16(Ab + (size_t)(seg0 + 1) * 16 * K + kk_, &As[(buf)][(seg0+1) * 512]);\
        if constexpr (BN == 64) {                                                   \
            gload16(Bb + kk_, &Bs[(buf)][wave * 512]);                              \
        } else {                                                                    \
            gload16(Bb + (size_t)seg0 * 16 * K + kk_, &Bs[(buf)][seg0 * 512]);      \
            gload16(Bb + (size_t)(seg0 + 1) * 16 * K + kk_, &Bs[(buf)][(seg0+1) * 512]); \
        }                                                                           \
    } while (0)

    #define COMPUTE(buf) do {                                                       \
        bf16x8 af[4], bfr[NJ];                                                      \
        _Pragma("unroll")                                                           \
        for (int i = 0; i < 4; ++i)                                                 \
            af[i] = *(bf16x8*)&As[(buf)][(wm + i * 16 + l16) * 32 + rslot];         \
        _Pragma("unroll")                                                           \
        for (int j = 0; j < NJ; ++j)                                                \
            bfr[j] = *(bf16x8*)&Bs[(buf)][(wn + j * 16 + l16) * 32 + rslot];        \
        _Pragma("unroll")                                                           \
        for (int i = 0; i < 4; ++i)                                                 \
            _Pragma("unroll")                                                       \
            for (int j = 0; j < NJ; ++j)                                            \
                acc[i][j] = __builtin_amdgcn_mfma_f32_16x16x32_bf16(                \
                    af[i], bfr[j], acc[i][j], 0, 0, 0);                             \
    } while (0)

    STAGE(0, 0);
    STAGE(1, 1);

    int cur = 0, pf = 2;
    for (int t = 0; t < nt - 1; ++t) {
        // wait for tile t's L loads (tile t+1's L stay in flight), then sync
        if constexpr (BN == 64) asm volatile("s_waitcnt vmcnt(3)" ::: "memory");
        else                    asm volatile("s_waitcnt vmcnt(4)" ::: "memory");
        __builtin_amdgcn_s_barrier();
        __builtin_amdgcn_sched_barrier(0);
        if (t + 2 < nt) STAGE(t + 2, pf);
        COMPUTE(cur);
        cur = (cur == 2) ? 0 : cur + 1;
        pf  = (pf  == 2) ? 0 : pf  + 1;
    }
    asm volatile("s_waitcnt vmcnt(0)" ::: "memory");
    __builtin_amdgcn_s_barrier();
    __builtin_amdgcn_sched_barrier(0);
    COMPUTE(cur);

    #undef STAGE
    #undef COMPUTE

#pragma unroll
    for (int j = 0; j < NJ; ++j) {
        int col = n0 + wn + j * 16 + l16;
        float bv = (bias && blockIdx.z == 0) ? bias[col] : 0.f;
#pragma unroll
        for (int i = 0; i < 4; ++i) {
            int rbase = m0 + wm + i * 16 + quad * 4;
#pragma unroll
            for (int r = 0; r < 4; ++r) {
                float vv = acc[i][j][r] + bv;
                if (act == 1) vv = gelu_exact(vv);
                if (Cfp) Cfp[(size_t)(rbase + r) * N + col] = vv;
                if (Cb) Cb[(size_t)(rbase + r) * N + col] = (bf16_t)vv;
            }
        }
    }
}

// ---------------- fused (partial-sum) residual add + LayerNorm (row = one block) ----------------
// z = a0 + a1(opt) + a2(opt) + a3(opt) + b(opt)
__global__ __launch_bounds__(256) void ln_fused_kernel(
    const float* __restrict__ a0, const float* __restrict__ a1,
    const float* __restrict__ a2, const float* __restrict__ a3,
    const float* __restrict__ b,
    const float* __restrict__ w, const float* __restrict__ beta,
    float* __restrict__ out, bf16_t* __restrict__ outb)
{
    long row = blockIdx.x;
    int tid = threadIdx.x;
    f32x4 z = *(const f32x4*)&a0[row * D_ + tid * 4];
    if (a1) z += *(const f32x4*)&a1[row * D_ + tid * 4];
    if (a2) z += *(const f32x4*)&a2[row * D_ + tid * 4];
    if (a3) z += *(const f32x4*)&a3[row * D_ + tid * 4];
    if (b)  z += *(const f32x4*)&b[row * D_ + tid * 4];
    float s  = z[0] + z[1] + z[2] + z[3];
    float ss = z[0]*z[0] + z[1]*z[1] + z[2]*z[2] + z[3]*z[3];
#pragma unroll
    for (int off = 32; off >= 1; off >>= 1) {
        s  += __shfl_down(s, off);
        ss += __shfl_down(ss, off);
    }
    __shared__ float red[8];
    int lane = tid & 63, wid = tid >> 6;
    if (lane == 0) { red[wid * 2] = s; red[wid * 2 + 1] = ss; }
    __syncthreads();
    s  = red[0] + red[2] + red[4] + red[6];
    ss = red[1] + red[3] + red[5] + red[7];
    float mean = s * (1.0f / D_);
    float var  = ss * (1.0f / D_) - mean * mean;
    float rs = rsqrtf(var + 1e-5f);
    f32x4 wv = *(const f32x4*)&w[tid * 4];
    f32x4 bv = *(const f32x4*)&beta[tid * 4];
    f32x4 o = (z - mean) * rs * wv + bv;
    *(f32x4*)&out[row * D_ + tid * 4] = o;
    if (outb) *(bf16x4*)&outb[row * D_ + tid * 4] = __builtin_convertvector(o, bf16x4);
}

// ---------------- host launch ----------------
extern "C" void kernel_launch(void* const* d_in, const int* in_sizes, int n_in,
                              void* d_out, int out_size, void* d_ws, size_t ws_size,
                              hipStream_t stream)
{
    (void)in_sizes; (void)n_in; (void)out_size; (void)ws_size;
    const float* x    = (const float*)d_in[0];
    const float* pos  = (const float*)d_in[1];
    const float* Wq   = (const float*)d_in[2];
    const float* bq   = (const float*)d_in[3];
    const float* Wk   = (const float*)d_in[4];
    const float* bk   = (const float*)d_in[5];
    const float* Wv   = (const float*)d_in[6];
    const float* bv   = (const float*)d_in[7];
    const float* Wfc  = (const float*)d_in[8];
    const float* bfc  = (const float*)d_in[9];
    const float* ln1w = (const float*)d_in[10];
    const float* ln1b = (const float*)d_in[11];
    const float* ln2w = (const float*)d_in[12];
    const float* ln2b = (const float*)d_in[13];
    const float* W1   = (const float*)d_in[14];
    const float* b1   = (const float*)d_in[15];
    const float* W2   = (const float*)d_in[16];
    const float* b2   = (const float*)d_in[17];
    const float* lnfw = (const float*)d_in[18];
    const float* lnfb = (const float*)d_in[19];

    const size_t MB = 1 << 20;
    char* ws = (char*)d_ws;
    float*  y    = (float*)(ws);             //  0-8   fp32 activations
    bf16_t* yb   = (bf16_t*)(ws + 8 * MB);   //  8-12  bf16 activations
    bf16_t* qb   = (bf16_t*)(ws + 12 * MB);  // 12-16
    bf16_t* kb   = (bf16_t*)(ws + 16 * MB);  // 16-20
    bf16_t* vb   = (bf16_t*)(ws + 20 * MB);  // 20-24
    bf16_t* ob   = (bf16_t*)(ws + 24 * MB);  // 24-28
    float*  t1a  = (float*)(ws + 12 * MB);   // 12-20  Wfc partial 0 (qb/kb dead after attn)
    float*  t1b  = (float*)(ws + 28 * MB);   // 28-36  Wfc partial 1 (aliases 'add'; ln1 reduces in place)
    float*  add  = (float*)(ws + 28 * MB);   // 28-36
    bf16_t* addb = (bf16_t*)(ws + 36 * MB);  // 36-40
    bf16_t* vTb  = (bf16_t*)(ws + 40 * MB);  // 40-44  V^T [b,h,d,s] (ffb region, dead here)
    bf16_t* ffb  = (bf16_t*)(ws + 40 * MB);  // 40-56
    bf16_t* WTall= (bf16_t*)(ws + 64 * MB);  // 64-172 all-layer weight transposes (18 MB/layer)
    float*  t2p  = (float*)(ws + 172 * MB);  // 172-204 FFN2 partials x4 (8 MB stride)

    const size_t pstride_wfc  = (size_t)16 * MB / sizeof(float); // t1b - t1a
    const size_t pstride_ffn2 = (size_t)8 * MB / sizeof(float);  // t2p stride
    const size_t LSTRIDE = 9437184;                              // bf16 elems per layer

    // all weight transposes in ONE launch, off the per-layer critical path
    tconv_all_kernel<<<27648, 256, 0, stream>>>(Wfc, W1, W2, WTall);

    add_pos_kernel<<<2048, 256, 0, stream>>>(x, pos, y, yb);

    for (int i = 0; i < NL_; ++i) {
        bf16_t* WfcT = WTall + (size_t)i * LSTRIDE;
        bf16_t* W1T  = WfcT + 1048576;
        bf16_t* W2T  = WfcT + 5242880;

        qkv_mfma_kernel<<<256, 256, 0, stream>>>(
            yb, Wq + i * 4096, bq + i * 64, Wk + i * 4096, bk + i * 64,
            Wv + i * 4096, bv + i * 64, qb, kb, vb);

        vtrans_kernel<<<dim3(32, 32), 256, 0, stream>>>(vb, vTb);

        attn_mfma_kernel<<<dim3(16, 32), 256, 0, stream>>>(qb, kb, vTb, ob);

        // ---- attention output projection: BN=64, split-K=2 -> 512 blocks ----
        gemm_bt_kernel<64><<<dim3(16, 16, 2), 256, 0, stream>>>(
            ob, WfcT, bfc + i * D_, t1a, nullptr, 2048, D_, D_, 0, pstride_wfc);

        ln_fused_kernel<<<2048, 256, 0, stream>>>(
            t1a, t1b, nullptr, nullptr, y, ln1w + i * D_, ln1b + i * D_, add, addb);

        // ---- FFN1: BN=128 -> 512 blocks, 16 MFMA/wave-step ----
        gemm_bt_kernel<128><<<dim3(16, 32, 1), 256, 0, stream>>>(
            addb, W1T, b1 + i * DFF_, nullptr, ffb, 2048, DFF_, D_, 1, 0);

        // ---- FFN2: BN=128, split-K=4 -> 512 blocks; 4 fp32 partials ----
        gemm_bt_kernel<128><<<dim3(16, 8, 4), 256, 0, stream>>>(
            ffb, W2T, b2 + i * D_, t2p, nullptr, 2048, D_, DFF_, 0, pstride_ffn2);

        ln_fused_kernel<<<2048, 256, 0, stream>>>(
            t2p, t2p + pstride_ffn2, t2p + 2 * pstride_ffn2, t2p + 3 * pstride_ffn2,
            add, ln2w + i * D_, ln2b + i * D_, y, yb);
    }

    ln_fused_kernel<<<2048, 256, 0, stream>>>(
        y, nullptr, nullptr, nullptr, nullptr, lnfw, lnfb, (float*)d_out, nullptr);
}